// Round 1
// baseline (276.927 us; speedup 1.0000x reference)
//
#include <hip/hip_runtime.h>
#include <hip/hip_bf16.h>
#include <cfloat>
#include <cmath>

// Problem constants (from setup_inputs): B=32, S=2048, H=1024, K=4, PREV=2, R=8
#define BB 32
#define SS 2048
#define HH 1024
#define KK 4

// ---------------------------------------------------------------------------
// Generic small GEMM: out[b,j] = sum_k A[b,k] * W[j,k] + bias[j]
// A: (32 x 1024), W: (N x 1024) row-major, out: (32 x N)
// grid.x = N/32, block = 256
// ---------------------------------------------------------------------------
__global__ __launch_bounds__(256) void gemm_abt(const float* __restrict__ A,
                                                const float* __restrict__ W,
                                                const float* __restrict__ bias,
                                                float* __restrict__ out, int N) {
  __shared__ float As[64 * 33];  // [kk][b], padded
  __shared__ float Ws[32 * 65];  // [j][kk], padded
  int t = threadIdx.x;
  int j0 = blockIdx.x * 32;
  int jl = t & 31;
  int bg = (t >> 5) * 4;
  float acc0 = 0.f, acc1 = 0.f, acc2 = 0.f, acc3 = 0.f;
  for (int k0 = 0; k0 < HH; k0 += 64) {
#pragma unroll
    for (int j = 0; j < 8; j++) {
      int e = t * 8 + j;  // 0..2047
      int rr = e >> 6, kk = e & 63;
      As[kk * 33 + rr] = A[rr * HH + k0 + kk];
      Ws[rr * 65 + kk] = W[(size_t)(j0 + rr) * HH + k0 + kk];
    }
    __syncthreads();
#pragma unroll
    for (int kk = 0; kk < 64; kk++) {
      float w = Ws[jl * 65 + kk];
      acc0 += As[kk * 33 + bg + 0] * w;
      acc1 += As[kk * 33 + bg + 1] * w;
      acc2 += As[kk * 33 + bg + 2] * w;
      acc3 += As[kk * 33 + bg + 3] * w;
    }
    __syncthreads();
  }
  float bs = bias[j0 + jl];
  out[(size_t)(bg + 0) * N + j0 + jl] = acc0 + bs;
  out[(size_t)(bg + 1) * N + j0 + jl] = acc1 + bs;
  out[(size_t)(bg + 2) * N + j0 + jl] = acc2 + bs;
  out[(size_t)(bg + 3) * N + j0 + jl] = acc3 + bs;
}

// ---------------------------------------------------------------------------
// GRU pointwise: h_new = (1-z)*n + z*h
// ---------------------------------------------------------------------------
__global__ __launch_bounds__(256) void gru_pointwise(const float* __restrict__ gi,
                                                     const float* __restrict__ gh,
                                                     const float* __restrict__ h_old,
                                                     float* __restrict__ h_new) {
  int i = blockIdx.x * 256 + threadIdx.x;  // 0..32767
  int b = i >> 10, h = i & 1023;
  float ir = gi[b * 3 * HH + h];
  float iz = gi[b * 3 * HH + HH + h];
  float in_ = gi[b * 3 * HH + 2 * HH + h];
  float hr = gh[b * 3 * HH + h];
  float hz = gh[b * 3 * HH + HH + h];
  float hn = gh[b * 3 * HH + 2 * HH + h];
  float r = 1.f / (1.f + expf(-(ir + hr)));
  float z = 1.f / (1.f + expf(-(iz + hz)));
  float n = tanhf(in_ + r * hn);
  h_new[i] = (1.f - z) * n + z * h_old[i];
}

// ---------------------------------------------------------------------------
// q_part[kc,b,n] = sum_{k in chunk kc} h_new[b,k] * Wk[k,n]
// grid = (4 n-tiles, 8 k-chunks), block = 256
// ---------------------------------------------------------------------------
__global__ __launch_bounds__(256) void q_partial(const float* __restrict__ hnew,
                                                 const float* __restrict__ Wk,
                                                 float* __restrict__ qpart) {
  __shared__ float Hs[BB * 128];
  int t = threadIdx.x;
  int n = blockIdx.x * 256 + t;
  int kbase = blockIdx.y * 128;
#pragma unroll
  for (int j = 0; j < 16; j++) {
    int e = t * 16 + j;  // 0..4095
    int bb = e >> 7, kk = e & 127;
    Hs[bb * 128 + kk] = hnew[bb * HH + kbase + kk];
  }
  __syncthreads();
  float acc[BB];
#pragma unroll
  for (int b = 0; b < BB; b++) acc[b] = 0.f;
  for (int k = 0; k < 128; k++) {
    float w = Wk[(size_t)(kbase + k) * HH + n];
#pragma unroll
    for (int b = 0; b < BB; b++) acc[b] += Hs[b * 128 + k] * w;
  }
#pragma unroll
  for (int b = 0; b < BB; b++)
    qpart[((size_t)blockIdx.y * BB + b) * HH + n] = acc[b];
}

__global__ __launch_bounds__(256) void q_reduce(const float* __restrict__ qpart,
                                                float* __restrict__ q) {
  int i = blockIdx.x * 256 + threadIdx.x;  // 0..32767
  float s = 0.f;
#pragma unroll
  for (int c = 0; c < 8; c++) s += qpart[(size_t)c * (BB * HH) + i];
  q[i] = s;
}

// hbk[b] = h_new[b,:] . bk
__global__ __launch_bounds__(256) void dot_hbk(const float* __restrict__ hnew,
                                               const float* __restrict__ bk,
                                               float* __restrict__ hbk) {
  __shared__ float red[256];
  int b = blockIdx.x, t = threadIdx.x;
  float s = 0.f;
  for (int k = t; k < HH; k += 256) s += hnew[b * HH + k] * bk[k];
  red[t] = s;
  __syncthreads();
  for (int o = 128; o; o >>= 1) {
    if (t < o) red[t] += red[t + o];
    __syncthreads();
  }
  if (t == 0) hbk[b] = red[0];
}

// ---------------------------------------------------------------------------
// logits[b,s] = (q[b,:].eo[b,s,:] + hbk[b]) / 32 + mask[b,s]
// one wave per (b,s); block = 4 waves; grid = 16384
// ---------------------------------------------------------------------------
__global__ __launch_bounds__(256) void logits_kernel(const float* __restrict__ eo,
                                                     const float* __restrict__ q,
                                                     const float* __restrict__ hbk,
                                                     const float* __restrict__ mask,
                                                     float* __restrict__ logits) {
  int wid = blockIdx.x * 4 + (threadIdx.x >> 6);
  int lane = threadIdx.x & 63;
  int b = wid >> 11, s = wid & (SS - 1);
  const float4* e4 = (const float4*)(eo + ((size_t)b * SS + s) * HH);
  const float4* q4 = (const float4*)(q + (size_t)b * HH);
  float acc = 0.f;
#pragma unroll
  for (int r = 0; r < 4; r++) {
    float4 e = e4[r * 64 + lane];
    float4 qq = q4[r * 64 + lane];
    acc += e.x * qq.x + e.y * qq.y + e.z * qq.z + e.w * qq.w;
  }
#pragma unroll
  for (int off = 32; off; off >>= 1) acc += __shfl_xor(acc, off);
  if (lane == 0)
    logits[(size_t)b * SS + s] = (acc + hbk[b]) * 0.03125f + mask[(size_t)b * SS + s];
}

// ---------------------------------------------------------------------------
// softmax over each row of logits -> alpha; also top-4 (value,index) per row
// grid = 32 (one block per b), block = 256
// ---------------------------------------------------------------------------
__global__ __launch_bounds__(256) void softmax_topk(const float* __restrict__ logits,
                                                    float* __restrict__ alpha,
                                                    float* __restrict__ scores,
                                                    int* __restrict__ sent) {
  __shared__ float row[SS];
  __shared__ float rv[256];
  __shared__ int ri[256];
  int b = blockIdx.x, t = threadIdx.x;
  for (int i = t; i < SS; i += 256) row[i] = logits[(size_t)b * SS + i];
  __syncthreads();
  float m = -FLT_MAX;
  for (int i = t; i < SS; i += 256) m = fmaxf(m, row[i]);
  rv[t] = m;
  __syncthreads();
  for (int o = 128; o; o >>= 1) {
    if (t < o) rv[t] = fmaxf(rv[t], rv[t + o]);
    __syncthreads();
  }
  m = rv[0];
  __syncthreads();
  float sum = 0.f;
  for (int i = t; i < SS; i += 256) sum += expf(row[i] - m);
  rv[t] = sum;
  __syncthreads();
  for (int o = 128; o; o >>= 1) {
    if (t < o) rv[t] += rv[t + o];
    __syncthreads();
  }
  sum = rv[0];
  __syncthreads();
  float inv = 1.f / sum;
  for (int i = t; i < SS; i += 256) alpha[(size_t)b * SS + i] = expf(row[i] - m) * inv;
  // top-4 (monotone in logit value); ties -> smallest index (matches lax.top_k)
  for (int k = 0; k < KK; k++) {
    float bv = -FLT_MAX;
    int bi = 1 << 30;
    for (int i = t; i < SS; i += 256) {
      float v = row[i];
      if (v > bv || (v == bv && i < bi)) { bv = v; bi = i; }
    }
    rv[t] = bv;
    ri[t] = bi;
    __syncthreads();
    for (int o = 128; o; o >>= 1) {
      if (t < o) {
        float v2 = rv[t + o]; int i2 = ri[t + o];
        if (v2 > rv[t] || (v2 == rv[t] && i2 < ri[t])) { rv[t] = v2; ri[t] = i2; }
      }
      __syncthreads();
    }
    if (t == 0) {
      scores[b * KK + k] = expf(rv[0] - m) * inv;
      sent[b * KK + k] = ri[0];
      row[ri[0]] = -FLT_MAX;
    }
    __syncthreads();
  }
}

// ---------------------------------------------------------------------------
// c0part[sc,b,h] = sum_{s in chunk sc (64 rows)} alpha[b,s] * eo[b,s,h]
// grid = (32 s-chunks, 32 b), block = 256 (each thread: one float4 of h)
// ---------------------------------------------------------------------------
__global__ __launch_bounds__(256) void c0_partial(const float* __restrict__ eo,
                                                  const float* __restrict__ alpha,
                                                  float* __restrict__ c0part) {
  __shared__ float a_s[64];
  int sc = blockIdx.x, b = blockIdx.y, t = threadIdx.x;
  int s0 = sc * 64;
  if (t < 64) a_s[t] = alpha[(size_t)b * SS + s0 + t];
  __syncthreads();
  const float4* e4 = (const float4*)(eo + ((size_t)b * SS + s0) * HH);
  float4 acc = {0.f, 0.f, 0.f, 0.f};
  for (int ss = 0; ss < 64; ss++) {
    float a = a_s[ss];
    float4 e = e4[(size_t)ss * 256 + t];
    acc.x += a * e.x; acc.y += a * e.y; acc.z += a * e.z; acc.w += a * e.w;
  }
  float4* o4 = (float4*)(c0part + ((size_t)sc * BB + b) * HH);
  o4[t] = acc;
}

__global__ __launch_bounds__(256) void c0_reduce(const float* __restrict__ c0part,
                                                 float* __restrict__ c0) {
  int i = blockIdx.x * 256 + threadIdx.x;  // 0..32767
  float s = 0.f;
#pragma unroll
  for (int c = 0; c < 32; c++) s += c0part[(size_t)c * (BB * HH) + i];
  c0[i] = s;
}

// ---------------------------------------------------------------------------
// Beam selection: per group r (8 groups), flat[16] = -log(scores)+evidence,
// take 4 smallest (stable, ascending). Writes out2 (indices as float), out5,
// and ssel (selected source batch per output slot).
// ---------------------------------------------------------------------------
__global__ void selection(const float* __restrict__ scores,
                          const int* __restrict__ sent,
                          const float* __restrict__ evidence,
                          const int* __restrict__ esi,
                          float* __restrict__ out2, float* __restrict__ out5,
                          int* __restrict__ ssel) {
  int r = threadIdx.x;
  if (r >= 8) return;
  float ls[16];
  for (int k1 = 0; k1 < 4; k1++)
    for (int k2 = 0; k2 < 4; k2++)
      ls[k1 * 4 + k2] = -logf(scores[(r * 4 + k1) * 4 + k2]) + evidence[r * 4 + k1];
  bool used[16];
  for (int i = 0; i < 16; i++) used[i] = false;
  for (int j = 0; j < 4; j++) {
    int best = 0;
    float bv = FLT_MAX;
    for (int i = 0; i < 16; i++)
      if (!used[i] && ls[i] < bv) { bv = ls[i]; best = i; }
    used[best] = true;
    int bout = r * 4 + j;
    int k1 = best >> 2, k2 = best & 3;
    int sSel = r * 4 + k1;
    ssel[bout] = sSel;
    out5[bout] = bv;
    out2[bout * 3 + 0] = (float)esi[sSel * 2 + 0];
    out2[bout * 3 + 1] = (float)esi[sSel * 2 + 1];
    out2[bout * 3 + 2] = (float)sent[sSel * 4 + k2];
  }
}

// ---------------------------------------------------------------------------
// Gather all row-shaped outputs by ssel
// grid = 32 (b_out), block = 256
// ---------------------------------------------------------------------------
__global__ __launch_bounds__(256) void gather_out(const float* __restrict__ ctx,
                                                  const float* __restrict__ hnew,
                                                  const float* __restrict__ attn_in,
                                                  const float* __restrict__ logits,
                                                  const float* __restrict__ mask,
                                                  const int* __restrict__ ssel,
                                                  float* __restrict__ out0,
                                                  float* __restrict__ out1,
                                                  float* __restrict__ out3,
                                                  float* __restrict__ out4) {
  int b = blockIdx.x, t = threadIdx.x;
  int s = ssel[b];
  {  // result (ctx row), hidden (h_new row): 1024 floats = 256 float4
    const float4* c4 = (const float4*)(ctx + (size_t)s * HH);
    float4* o0 = (float4*)(out0 + (size_t)b * HH);
    o0[t] = c4[t];
    const float4* h4 = (const float4*)(hnew + (size_t)s * HH);
    float4* o1 = (float4*)(out1 + (size_t)b * HH);
    o1[t] = h4[t];
  }
#pragma unroll
  for (int p = 0; p < 2; p++) {
    const float4* src = (const float4*)(attn_in + ((size_t)p * BB + s) * SS);
    float4* dst = (float4*)(out3 + ((size_t)p * BB + b) * SS);
    dst[t] = src[t];
    dst[t + 256] = src[t + 256];
  }
  {
    const float4* lg = (const float4*)(logits + (size_t)s * SS);
    float4* d2 = (float4*)(out3 + ((size_t)2 * BB + b) * SS);
    d2[t] = lg[t];
    d2[t + 256] = lg[t + 256];
    const float4* mk = (const float4*)(mask + (size_t)s * SS);
    float4* d4 = (float4*)(out4 + (size_t)b * SS);
    d4[t] = mk[t];
    d4[t + 256] = mk[t + 256];
  }
}

extern "C" void kernel_launch(void* const* d_in, const int* in_sizes, int n_in,
                              void* d_out, int out_size, void* d_ws, size_t ws_size,
                              hipStream_t stream) {
  const float* h_old = (const float*)d_in[0];    // (1,B,H)
  const float* x     = (const float*)d_in[1];    // (B,1,H)
  const float* eo    = (const float*)d_in[2];    // (B,S,H)
  const float* attn_in = (const float*)d_in[3];  // (2,B,1,S)
  const float* mask  = (const float*)d_in[4];    // (B,1,S)
  const float* evidence = (const float*)d_in[5]; // (B,)
  const int*   esi   = (const int*)d_in[6];      // (B,2)
  const float* W_ih  = (const float*)d_in[7];
  const float* W_hh  = (const float*)d_in[8];
  const float* b_ih  = (const float*)d_in[9];
  const float* b_hh  = (const float*)d_in[10];
  const float* Wk    = (const float*)d_in[11];
  const float* bk    = (const float*)d_in[12];
  const float* Wv    = (const float*)d_in[13];
  const float* bv    = (const float*)d_in[14];

  float* w = (float*)d_ws;
  // persistent buffers
  float* h_new  = w + 0;        // 32768
  float* q      = w + 32768;    // 32768
  float* hbk    = w + 65536;    // 32
  float* logits = w + 65568;    // 65536
  float* alpha  = w + 131104;   // 65536
  float* scores = w + 196640;   // 128
  int*   sent   = (int*)(w + 196768);  // 128
  int*   ssel   = (int*)(w + 196896); // 32
  float* c0     = w + 196928;   // 32768
  float* ctx    = w + 229696;   // 32768
  // transient region (reused): gi/gh, then qpart, then c0part
  float* gi     = w + 262464;   // 98304
  float* gh     = w + 360768;   // 98304
  float* qpart  = w + 262464;   // 262144 (gi/gh dead by then)
  float* c0part = w + 262464;   // 1048576 (qpart dead by then)

  // outputs (all float32 in d_out, concatenated flat in return order)
  float* out0 = (float*)d_out;          // result (32,1,1024)
  float* out1 = out0 + 32768;           // hidden (1,32,1024)
  float* out2 = out1 + 32768;           // new_evidence_sentence_index (32,3)
  float* out3 = out2 + 96;              // new_attention_scores (3,32,1,2048)
  float* out4 = out3 + 196608;          // new_attention_mask (32,1,2048)
  float* out5 = out4 + 65536;           // new_evidence_scores (32,)

  // 1-2: GRU gate GEMMs
  gemm_abt<<<96, 256, 0, stream>>>(x, W_ih, b_ih, gi, 3 * HH);
  gemm_abt<<<96, 256, 0, stream>>>(h_old, W_hh, b_hh, gh, 3 * HH);
  // 3: GRU pointwise
  gru_pointwise<<<128, 256, 0, stream>>>(gi, gh, h_old, h_new);
  // 4-5: q = h_new @ Wk (split-k partials + reduce)
  q_partial<<<dim3(4, 8), 256, 0, stream>>>(h_new, Wk, qpart);
  q_reduce<<<128, 256, 0, stream>>>(qpart, q);
  // 6: hbk = h_new . bk
  dot_hbk<<<BB, 256, 0, stream>>>(h_new, bk, hbk);
  // 7: attention logits (= attn_outputs, pre-softmax incl. mask)
  logits_kernel<<<(BB * SS) / 4, 256, 0, stream>>>(eo, q, hbk, mask, logits);
  // 8: softmax + per-row top-4
  softmax_topk<<<BB, 256, 0, stream>>>(logits, alpha, scores, sent);
  // 9-10: c0 = sum_s alpha * eo
  c0_partial<<<dim3(32, BB), 256, 0, stream>>>(eo, alpha, c0part);
  c0_reduce<<<128, 256, 0, stream>>>(c0part, c0);
  // 11: context = c0 @ Wv.T + bv
  gemm_abt<<<32, 256, 0, stream>>>(c0, Wv, bv, ctx, HH);
  // 12: beam selection + small outputs
  selection<<<1, 64, 0, stream>>>(scores, sent, evidence, esi, out2, out5, ssel);
  // 13: gather row outputs
  gather_out<<<BB, 256, 0, stream>>>(ctx, h_new, attn_in, logits, mask, ssel,
                                     out0, out1, out3, out4);
}

// Round 2
// 226.750 us; speedup vs baseline: 1.2213x; 1.2213x over previous
//
#include <hip/hip_runtime.h>
#include <hip/hip_bf16.h>
#include <cfloat>
#include <cmath>

// Problem constants: B=32, S=2048, H=1024, K=4, PREV=2, R=8
#define BB 32
#define SS 2048
#define HH 1024
#define KK 4
#define CH 32  // s-chunks per batch row in fused_attn (64 rows each)

// ---------------------------------------------------------------------------
// Fused GRU gate GEMMs: blockIdx.y=0 -> gi = x @ W_ih.T + b_ih
//                       blockIdx.y=1 -> gh = h_old @ W_hh.T + b_hh
// grid (96, 2), block 256
// ---------------------------------------------------------------------------
__global__ __launch_bounds__(256) void gemm_gates(const float* __restrict__ x,
                                                  const float* __restrict__ h_old,
                                                  const float* __restrict__ W_ih,
                                                  const float* __restrict__ W_hh,
                                                  const float* __restrict__ b_ih,
                                                  const float* __restrict__ b_hh,
                                                  float* __restrict__ gi,
                                                  float* __restrict__ gh) {
  const int N = 3 * HH;
  const float* A = blockIdx.y ? h_old : x;
  const float* W = blockIdx.y ? W_hh : W_ih;
  const float* bias = blockIdx.y ? b_hh : b_ih;
  float* out = blockIdx.y ? gh : gi;

  __shared__ float As[64 * 33];
  __shared__ float Ws[32 * 65];
  int t = threadIdx.x;
  int j0 = blockIdx.x * 32;
  int jl = t & 31;
  int bg = (t >> 5) * 4;
  float acc0 = 0.f, acc1 = 0.f, acc2 = 0.f, acc3 = 0.f;
  for (int k0 = 0; k0 < HH; k0 += 64) {
#pragma unroll
    for (int j = 0; j < 8; j++) {
      int e = t * 8 + j;
      int rr = e >> 6, kk = e & 63;
      As[kk * 33 + rr] = A[rr * HH + k0 + kk];
      Ws[rr * 65 + kk] = W[(size_t)(j0 + rr) * HH + k0 + kk];
    }
    __syncthreads();
#pragma unroll
    for (int kk = 0; kk < 64; kk++) {
      float w = Ws[jl * 65 + kk];
      acc0 += As[kk * 33 + bg + 0] * w;
      acc1 += As[kk * 33 + bg + 1] * w;
      acc2 += As[kk * 33 + bg + 2] * w;
      acc3 += As[kk * 33 + bg + 3] * w;
    }
    __syncthreads();
  }
  float bs = bias[j0 + jl];
  out[(size_t)(bg + 0) * N + j0 + jl] = acc0 + bs;
  out[(size_t)(bg + 1) * N + j0 + jl] = acc1 + bs;
  out[(size_t)(bg + 2) * N + j0 + jl] = acc2 + bs;
  out[(size_t)(bg + 3) * N + j0 + jl] = acc3 + bs;
}

// Plain small GEMM for the context projection: out = A @ W.T + bias
__global__ __launch_bounds__(256) void gemm_abt(const float* __restrict__ A,
                                                const float* __restrict__ W,
                                                const float* __restrict__ bias,
                                                float* __restrict__ out, int N) {
  __shared__ float As[64 * 33];
  __shared__ float Ws[32 * 65];
  int t = threadIdx.x;
  int j0 = blockIdx.x * 32;
  int jl = t & 31;
  int bg = (t >> 5) * 4;
  float acc0 = 0.f, acc1 = 0.f, acc2 = 0.f, acc3 = 0.f;
  for (int k0 = 0; k0 < HH; k0 += 64) {
#pragma unroll
    for (int j = 0; j < 8; j++) {
      int e = t * 8 + j;
      int rr = e >> 6, kk = e & 63;
      As[kk * 33 + rr] = A[rr * HH + k0 + kk];
      Ws[rr * 65 + kk] = W[(size_t)(j0 + rr) * HH + k0 + kk];
    }
    __syncthreads();
#pragma unroll
    for (int kk = 0; kk < 64; kk++) {
      float w = Ws[jl * 65 + kk];
      acc0 += As[kk * 33 + bg + 0] * w;
      acc1 += As[kk * 33 + bg + 1] * w;
      acc2 += As[kk * 33 + bg + 2] * w;
      acc3 += As[kk * 33 + bg + 3] * w;
    }
    __syncthreads();
  }
  float bs = bias[j0 + jl];
  out[(size_t)(bg + 0) * N + j0 + jl] = acc0 + bs;
  out[(size_t)(bg + 1) * N + j0 + jl] = acc1 + bs;
  out[(size_t)(bg + 2) * N + j0 + jl] = acc2 + bs;
  out[(size_t)(bg + 3) * N + j0 + jl] = acc3 + bs;
}

// ---------------------------------------------------------------------------
// GRU pointwise
// ---------------------------------------------------------------------------
__global__ __launch_bounds__(256) void gru_pointwise(const float* __restrict__ gi,
                                                     const float* __restrict__ gh,
                                                     const float* __restrict__ h_old,
                                                     float* __restrict__ h_new) {
  int i = blockIdx.x * 256 + threadIdx.x;
  int b = i >> 10, h = i & 1023;
  float ir = gi[b * 3 * HH + h];
  float iz = gi[b * 3 * HH + HH + h];
  float in_ = gi[b * 3 * HH + 2 * HH + h];
  float hr = gh[b * 3 * HH + h];
  float hz = gh[b * 3 * HH + HH + h];
  float hn = gh[b * 3 * HH + 2 * HH + h];
  float r = 1.f / (1.f + expf(-(ir + hr)));
  float z = 1.f / (1.f + expf(-(iz + hz)));
  float n = tanhf(in_ + r * hn);
  h_new[i] = (1.f - z) * n + z * h_old[i];
}

// ---------------------------------------------------------------------------
// q_part[kc,b,n] = sum_{k in 32-chunk kc} h_new[b,k] * Wk[k,n]
// grid = (4 n-tiles, 32 k-chunks), block = 256
// ---------------------------------------------------------------------------
__global__ __launch_bounds__(256) void q_partial(const float* __restrict__ hnew,
                                                 const float* __restrict__ Wk,
                                                 float* __restrict__ qpart) {
  __shared__ float Hs[BB * 32];
  int t = threadIdx.x;
  int n = blockIdx.x * 256 + t;
  int kbase = blockIdx.y * 32;
#pragma unroll
  for (int j = 0; j < 4; j++) {
    int e = t * 4 + j;  // 0..1023
    int bb = e >> 5, kk = e & 31;
    Hs[bb * 32 + kk] = hnew[bb * HH + kbase + kk];
  }
  __syncthreads();
  float acc[BB];
#pragma unroll
  for (int b = 0; b < BB; b++) acc[b] = 0.f;
  for (int k = 0; k < 32; k++) {
    float w = Wk[(size_t)(kbase + k) * HH + n];
#pragma unroll
    for (int b = 0; b < BB; b++) acc[b] += Hs[b * 32 + k] * w;
  }
#pragma unroll
  for (int b = 0; b < BB; b++)
    qpart[((size_t)blockIdx.y * BB + b) * HH + n] = acc[b];
}

// blocks 0..127: reduce qpart -> q.  block 128: hbk[b] = h_new[b,:].bk
__global__ __launch_bounds__(256) void q_reduce_hbk(const float* __restrict__ qpart,
                                                    const float* __restrict__ hnew,
                                                    const float* __restrict__ bk,
                                                    float* __restrict__ q,
                                                    float* __restrict__ hbk) {
  int t = threadIdx.x;
  if (blockIdx.x < 128) {
    int i = blockIdx.x * 256 + t;
    float s = 0.f;
#pragma unroll
    for (int c = 0; c < 32; c++) s += qpart[(size_t)c * (BB * HH) + i];
    q[i] = s;
  } else {
    __shared__ float red[256];
    // 32 rows of 1024; each group of 8 threads handles one b? simpler: loop b
    for (int b = 0; b < BB; b++) {
      float s = 0.f;
      for (int k = t; k < HH; k += 256) s += hnew[b * HH + k] * bk[k];
      red[t] = s;
      __syncthreads();
      for (int o = 128; o; o >>= 1) {
        if (t < o) red[t] += red[t + o];
        __syncthreads();
      }
      if (t == 0) hbk[b] = red[0];
      __syncthreads();
    }
  }
}

// ---------------------------------------------------------------------------
// Fused attention pass (single HBM read of eo):
// per block (chunk sc of 64 rows, batch b):
//   - load 16 rows at a time into registers (float4/thread)
//   - logits: per-thread dot4 + wave butterfly + cross-wave LDS combine
//   - online softmax accumulate: acc += exp(l - m_running) * row
// writes: logits (global), c0part[sc,b,:] (unnormalized), msum_part[sc,b]={m,sum}
// grid (CH, BB), block 256
// ---------------------------------------------------------------------------
__global__ __launch_bounds__(256) void fused_attn(const float* __restrict__ eo,
                                                  const float* __restrict__ q,
                                                  const float* __restrict__ hbk,
                                                  const float* __restrict__ mask,
                                                  float* __restrict__ logits,
                                                  float* __restrict__ c0part,
                                                  float* __restrict__ msum_part) {
  __shared__ float wred[4][16];
  __shared__ float ls[16];
  int b = blockIdx.y, sc = blockIdx.x, t = threadIdx.x;
  int wave = t >> 6, lane = t & 63;
  float4 qv = ((const float4*)(q + (size_t)b * HH))[t];
  float hb = hbk[b];
  float m = -FLT_MAX, sum = 0.f;
  float4 acc = {0.f, 0.f, 0.f, 0.f};
  int s0 = sc * 64;
  for (int st = 0; st < 4; ++st) {
    int srow = s0 + st * 16;
    const float4* e4 = (const float4*)(eo + ((size_t)b * SS + srow) * HH);
    float4 r[16];
#pragma unroll
    for (int s = 0; s < 16; s++) r[s] = e4[(size_t)s * 256 + t];
    float p[16];
#pragma unroll
    for (int s = 0; s < 16; s++)
      p[s] = r[s].x * qv.x + r[s].y * qv.y + r[s].z * qv.z + r[s].w * qv.w;
#pragma unroll
    for (int off = 32; off; off >>= 1) {
#pragma unroll
      for (int s = 0; s < 16; s++) p[s] += __shfl_xor(p[s], off);
    }
    if (lane == 0) {
#pragma unroll
      for (int s = 0; s < 16; s++) wred[wave][s] = p[s];
    }
    __syncthreads();
    if (t < 16) {
      float lv = wred[0][t] + wred[1][t] + wred[2][t] + wred[3][t];
      lv = (lv + hb) * 0.03125f + mask[(size_t)b * SS + srow + t];
      logits[(size_t)b * SS + srow + t] = lv;
      ls[t] = lv;
    }
    __syncthreads();
    float tm = ls[0];
#pragma unroll
    for (int s = 1; s < 16; s++) tm = fmaxf(tm, ls[s]);
    float m_new = fmaxf(m, tm);
    float scale = expf(m - m_new);  // exp(-inf)=0 on first tile
    acc.x *= scale; acc.y *= scale; acc.z *= scale; acc.w *= scale;
    sum *= scale;
#pragma unroll
    for (int s = 0; s < 16; s++) {
      float w = expf(ls[s] - m_new);
      sum += w;
      acc.x += w * r[s].x; acc.y += w * r[s].y;
      acc.z += w * r[s].z; acc.w += w * r[s].w;
    }
    m = m_new;
    __syncthreads();
  }
  ((float4*)(c0part + ((size_t)sc * BB + b) * HH))[t] = acc;
  if (t == 0) {
    msum_part[((size_t)sc * BB + b) * 2 + 0] = m;
    msum_part[((size_t)sc * BB + b) * 2 + 1] = sum;
  }
}

// ---------------------------------------------------------------------------
// Combine chunks: c0[b,:] = (sum_c exp(m_c-m) * c0part[c,b,:]) / sum
// also writes msum[b] = {m, sum}.  grid 32, block 256
// ---------------------------------------------------------------------------
__global__ __launch_bounds__(256) void attn_reduce(const float* __restrict__ c0part,
                                                   const float* __restrict__ msum_part,
                                                   float* __restrict__ c0,
                                                   float* __restrict__ msum) {
  __shared__ float ms[CH], ssv[CH];
  int b = blockIdx.x, t = threadIdx.x;
  if (t < CH) {
    ms[t] = msum_part[((size_t)t * BB + b) * 2 + 0];
    ssv[t] = msum_part[((size_t)t * BB + b) * 2 + 1];
  }
  __syncthreads();
  float m = ms[0];
#pragma unroll
  for (int c = 1; c < CH; c++) m = fmaxf(m, ms[c]);
  float w[CH];
  float sum = 0.f;
#pragma unroll
  for (int c = 0; c < CH; c++) {
    w[c] = expf(ms[c] - m);
    sum += ssv[c] * w[c];
  }
  float inv = 1.f / sum;
  float4 acc = {0.f, 0.f, 0.f, 0.f};
#pragma unroll
  for (int c = 0; c < CH; c++) {
    float4 v = ((const float4*)(c0part + ((size_t)c * BB + b) * HH))[t];
    acc.x += w[c] * v.x; acc.y += w[c] * v.y;
    acc.z += w[c] * v.z; acc.w += w[c] * v.w;
  }
  acc.x *= inv; acc.y *= inv; acc.z *= inv; acc.w *= inv;
  ((float4*)(c0 + (size_t)b * HH))[t] = acc;
  if (t == 0) {
    msum[b * 2 + 0] = m;
    msum[b * 2 + 1] = sum;
  }
}

// ---------------------------------------------------------------------------
// Top-4 per row from logits; scores = exp(v - m) / sum
// grid 32, block 256
// ---------------------------------------------------------------------------
__global__ __launch_bounds__(256) void topk_scores(const float* __restrict__ logits,
                                                   const float* __restrict__ msum,
                                                   float* __restrict__ scores,
                                                   int* __restrict__ sent) {
  __shared__ float row[SS];
  __shared__ float rv[256];
  __shared__ int ri[256];
  int b = blockIdx.x, t = threadIdx.x;
  for (int i = t; i < SS; i += 256) row[i] = logits[(size_t)b * SS + i];
  __syncthreads();
  float m = msum[b * 2 + 0];
  float inv = 1.f / msum[b * 2 + 1];
  for (int k = 0; k < KK; k++) {
    float bv = -FLT_MAX;
    int bi = 1 << 30;
    for (int i = t; i < SS; i += 256) {
      float v = row[i];
      if (v > bv || (v == bv && i < bi)) { bv = v; bi = i; }
    }
    rv[t] = bv;
    ri[t] = bi;
    __syncthreads();
    for (int o = 128; o; o >>= 1) {
      if (t < o) {
        float v2 = rv[t + o]; int i2 = ri[t + o];
        if (v2 > rv[t] || (v2 == rv[t] && i2 < ri[t])) { rv[t] = v2; ri[t] = i2; }
      }
      __syncthreads();
    }
    if (t == 0) {
      scores[b * KK + k] = expf(rv[0] - m) * inv;
      sent[b * KK + k] = ri[0];
      row[ri[0]] = -FLT_MAX;
    }
    __syncthreads();
  }
}

// ---------------------------------------------------------------------------
// Selection (recomputed redundantly per output block) + gather of row outputs
// grid 32 (output b), block 256
// ---------------------------------------------------------------------------
__global__ __launch_bounds__(256) void sel_gather(const float* __restrict__ scores,
                                                  const int* __restrict__ sent,
                                                  const float* __restrict__ evidence,
                                                  const int* __restrict__ esi,
                                                  const float* __restrict__ ctx,
                                                  const float* __restrict__ hnew,
                                                  const float* __restrict__ attn_in,
                                                  const float* __restrict__ logits,
                                                  const float* __restrict__ mask,
                                                  float* __restrict__ out0,
                                                  float* __restrict__ out1,
                                                  float* __restrict__ out2,
                                                  float* __restrict__ out3,
                                                  float* __restrict__ out4,
                                                  float* __restrict__ out5) {
  __shared__ int s_sh;
  int b = blockIdx.x, t = threadIdx.x;
  if (t == 0) {
    int r = b >> 2, j = b & 3;
    float ls[16];
    bool used[16];
    for (int k1 = 0; k1 < 4; k1++)
      for (int k2 = 0; k2 < 4; k2++)
        ls[k1 * 4 + k2] = -logf(scores[(r * 4 + k1) * 4 + k2]) + evidence[r * 4 + k1];
    for (int i = 0; i < 16; i++) used[i] = false;
    int best = 0;
    float bv = FLT_MAX;
    for (int jj = 0; jj <= j; jj++) {
      best = 0;
      bv = FLT_MAX;
      for (int i = 0; i < 16; i++)
        if (!used[i] && ls[i] < bv) { bv = ls[i]; best = i; }
      used[best] = true;
    }
    int k1 = best >> 2, k2 = best & 3;
    int sSel = r * 4 + k1;
    s_sh = sSel;
    out5[b] = bv;
    out2[b * 3 + 0] = (float)esi[sSel * 2 + 0];
    out2[b * 3 + 1] = (float)esi[sSel * 2 + 1];
    out2[b * 3 + 2] = (float)sent[sSel * 4 + k2];
  }
  __syncthreads();
  int s = s_sh;
  {
    ((float4*)(out0 + (size_t)b * HH))[t] = ((const float4*)(ctx + (size_t)s * HH))[t];
    ((float4*)(out1 + (size_t)b * HH))[t] = ((const float4*)(hnew + (size_t)s * HH))[t];
  }
#pragma unroll
  for (int p = 0; p < 2; p++) {
    const float4* src = (const float4*)(attn_in + ((size_t)p * BB + s) * SS);
    float4* dst = (float4*)(out3 + ((size_t)p * BB + b) * SS);
    dst[t] = src[t];
    dst[t + 256] = src[t + 256];
  }
  {
    const float4* lg = (const float4*)(logits + (size_t)s * SS);
    float4* d2 = (float4*)(out3 + ((size_t)2 * BB + b) * SS);
    d2[t] = lg[t];
    d2[t + 256] = lg[t + 256];
    const float4* mk = (const float4*)(mask + (size_t)s * SS);
    float4* d4 = (float4*)(out4 + (size_t)b * SS);
    d4[t] = mk[t];
    d4[t + 256] = mk[t + 256];
  }
}

extern "C" void kernel_launch(void* const* d_in, const int* in_sizes, int n_in,
                              void* d_out, int out_size, void* d_ws, size_t ws_size,
                              hipStream_t stream) {
  const float* h_old = (const float*)d_in[0];
  const float* x     = (const float*)d_in[1];
  const float* eo    = (const float*)d_in[2];
  const float* attn_in = (const float*)d_in[3];
  const float* mask  = (const float*)d_in[4];
  const float* evidence = (const float*)d_in[5];
  const int*   esi   = (const int*)d_in[6];
  const float* W_ih  = (const float*)d_in[7];
  const float* W_hh  = (const float*)d_in[8];
  const float* b_ih  = (const float*)d_in[9];
  const float* b_hh  = (const float*)d_in[10];
  const float* Wk    = (const float*)d_in[11];
  const float* bk    = (const float*)d_in[12];
  const float* Wv    = (const float*)d_in[13];
  const float* bv    = (const float*)d_in[14];

  float* w = (float*)d_ws;
  // persistent
  float* h_new  = w + 0;        // 32768
  float* q      = w + 32768;    // 32768
  float* hbk    = w + 65536;    // 32
  float* logits = w + 65568;    // 65536
  float* scores = w + 131104;   // 128
  int*   sent   = (int*)(w + 131232);  // 128
  float* msum   = w + 131360;   // 64
  float* c0     = w + 131424;   // 32768
  float* ctx    = w + 164192;   // 32768
  float* msum_part = w + 196960; // 2048
  // transient (reused): gi/gh then qpart then c0part (max 1,048,576 floats)
  float* trans  = w + 199008;
  float* gi     = trans;            // 98304
  float* gh     = trans + 98304;    // 98304
  float* qpart  = trans;            // 1,048,576 (gi/gh dead)
  float* c0part = trans;            // 1,048,576 (qpart dead)

  // outputs (concatenated flat in return order)
  float* out0 = (float*)d_out;          // result (32,1,1024)
  float* out1 = out0 + 32768;           // hidden (1,32,1024)
  float* out2 = out1 + 32768;           // new_evidence_sentence_index (32,3)
  float* out3 = out2 + 96;              // new_attention_scores (3,32,1,2048)
  float* out4 = out3 + 196608;          // new_attention_mask (32,1,2048)
  float* out5 = out4 + 65536;           // new_evidence_scores (32,)

  gemm_gates<<<dim3(96, 2), 256, 0, stream>>>(x, h_old, W_ih, W_hh, b_ih, b_hh, gi, gh);
  gru_pointwise<<<128, 256, 0, stream>>>(gi, gh, h_old, h_new);
  q_partial<<<dim3(4, 32), 256, 0, stream>>>(h_new, Wk, qpart);
  q_reduce_hbk<<<129, 256, 0, stream>>>(qpart, h_new, bk, q, hbk);
  fused_attn<<<dim3(CH, BB), 256, 0, stream>>>(eo, q, hbk, mask, logits, c0part, msum_part);
  attn_reduce<<<BB, 256, 0, stream>>>(c0part, msum_part, c0, msum);
  topk_scores<<<BB, 256, 0, stream>>>(logits, msum, scores, sent);
  gemm_abt<<<32, 256, 0, stream>>>(c0, Wv, bv, ctx, HH);
  sel_gather<<<BB, 256, 0, stream>>>(scores, sent, evidence, esi, ctx, h_new,
                                     attn_in, logits, mask,
                                     out0, out1, out2, out3, out4, out5);
}